// Round 8
// baseline (523.781 us; speedup 1.0000x reference)
//
#include <hip/hip_runtime.h>
#include <math.h>

// All inputs and the output are FLOAT32 (reference dtype).

#define HH 512
#define WWI 512
#define HWP (HH*WWI)

// ---------------- layer 0: 1x1 conv on upsampled 2x2 + leakyrelu + coordconv ----------------
__global__ void k_layer0(const float* __restrict__ xin, const float* __restrict__ w,
                         const float* __restrict__ bias, float* __restrict__ out)
{
  for (int idx = threadIdx.x; idx < 3*66*4; idx += blockDim.x) {
    int pos = idx & 3;
    int c = (idx >> 2) % 66;
    int b = idx / (66*4);
    float v;
    if (c < 64) {
      float a = bias[c];
      #pragma unroll
      for (int ci = 0; ci < 3; ci++) a += w[c*3+ci] * xin[b*3+ci];
      v = (a >= 0.f) ? a : 0.01f*a;
    } else {
      int xx = pos & 1, yy = pos >> 1;
      v = (c == 64) ? 2.f*(float)xx : 2.f*(float)yy;
    }
    out[idx] = v;
  }
}

__device__ __forceinline__ int refl_up(int t, int n) {
  t = (t < 0) ? -t : t;
  t = (t >= n) ? (2*(n-1) - t) : t;
  return t >> 1;
}

// ---------------- LDS conv for small layers L1-L5 (R7-proven) ----------------
template<int G>
__global__ void k_conv_lds(const float* __restrict__ in, float* __restrict__ out,
                           const float* __restrict__ w, const float* __restrict__ bias,
                           int B, int Cin, int CO, int COB, int Hin, int TR, int SPAN)
{
  extern __shared__ float lds[];
  const int Hout = Hin * 2;
  const int rowTiles = Hout / TR;
  const int coTiles = CO / COB;
  int bid = blockIdx.x;
  int tile = bid % rowTiles;
  int cot  = (bid / rowTiles) % coTiles;
  int b    = bid / (rowTiles * coTiles);
  int tr0  = tile * TR;
  int co_base = cot * COB;

  int r0 = tr0/2 - 1;
  if (r0 < 0) r0 = 0;
  if (r0 > Hin - SPAN) r0 = Hin - SPAN;

  float* wlds = lds;
  float* blds = wlds + COB*Cin*9;
  float* ilds = blds + COB;

  int nt = blockDim.x, tid = threadIdx.x;

  const float* wsrc = w + (size_t)co_base*Cin*9;
  for (int i = tid; i < COB*Cin*9; i += nt) wlds[i] = wsrc[i];
  for (int i = tid; i < COB; i += nt) blds[i] = bias[co_base + i];
  int icount = Cin*SPAN*Hin;
  for (int i = tid; i < icount; i += nt) {
    int col = i % Hin;
    int r = (i / Hin) % SPAN;
    int ci = i / (Hin*SPAN);
    ilds[i] = in[(((size_t)b*Cin + ci)*Hin + (r0 + r))*Hin + col];
  }
  __syncthreads();

  int npix = TR * Hout;
  int ngr = COB / G;
  int items = ngr * npix;
  for (int it = tid; it < items; it += nt) {
    int pix = it % npix;
    int cg = it / npix;
    int x = pix % Hout;
    int y = tr0 + pix / Hout;

    int ry[3], rx[3];
    #pragma unroll
    for (int d = 0; d < 3; d++) {
      int s = refl_up(y - 1 + d, Hout) - r0;
      s = (s < 0) ? 0 : s;
      s = (s > SPAN-1) ? SPAN-1 : s;
      ry[d] = s;
      rx[d] = refl_up(x - 1 + d, Hout);
    }

    float acc[G];
    #pragma unroll
    for (int j = 0; j < G; j++) acc[j] = blds[cg*G + j];

    for (int ci = 0; ci < Cin; ci++) {
      const float* ib = ilds + (size_t)ci*SPAN*Hin;
      float p[9];
      #pragma unroll
      for (int dy = 0; dy < 3; dy++)
        #pragma unroll
        for (int dx = 0; dx < 3; dx++)
          p[dy*3+dx] = ib[ry[dy]*Hin + rx[dx]];
      const float* wc = wlds + ((size_t)(cg*G)*Cin + ci)*9;
      #pragma unroll
      for (int j = 0; j < G; j++) {
        #pragma unroll
        for (int k = 0; k < 9; k++) acc[j] += wc[(size_t)j*Cin*9 + k] * p[k];
      }
    }

    #pragma unroll
    for (int j = 0; j < G; j++) {
      float v = acc[j];
      v = (v >= 0.f) ? v : 0.01f*v;
      out[(((size_t)b*CO + co_base + cg*G + j)*Hout + y)*Hout + x] = v;
    }
  }
}

// ---------------- phase-weight builder: 3x3 -> 4 phase 2x2 combined weights ----------------
// wq layout: [ci][co][py][px][ry2][rx2]  (16 floats per (ci,co))
__global__ void k_mkphase(const float* __restrict__ w, float* __restrict__ wq, int CO, int Cin)
{
  int tid = blockIdx.x*blockDim.x + threadIdx.x;
  if (tid >= CO*Cin) return;
  int co = tid / Cin;
  int ci = tid % Cin;
  const float* ws = w + (size_t)(co*Cin + ci)*9;
  float* o = wq + ((size_t)ci*CO + co)*16;
  // rowset[py][ry2] over taps {0,1,2}: py=0: {0},{1,2} ; py=1: {0,1},{2}
  #pragma unroll
  for (int py = 0; py < 2; py++)
    #pragma unroll
    for (int px = 0; px < 2; px++)
      #pragma unroll
      for (int ry = 0; ry < 2; ry++)
        #pragma unroll
        for (int rx = 0; rx < 2; rx++) {
          float s = 0.f;
          #pragma unroll
          for (int dy = 0; dy < 3; dy++) {
            bool yin = (py==0) ? ((ry==0) ? (dy==0) : (dy==1||dy==2))
                               : ((ry==0) ? (dy==0||dy==1) : (dy==2));
            if (!yin) continue;
            #pragma unroll
            for (int dx = 0; dx < 3; dx++) {
              bool xin_ = (px==0) ? ((rx==0) ? (dx==0) : (dx==1||dx==2))
                                  : ((rx==0) ? (dx==0||dx==1) : (dx==2));
              if (xin_) s += ws[dy*3+dx];
            }
          }
          o[((py*2+px)*2+ry)*2+rx] = s;
        }
}

// ---------------- phase-decomposed upconv: thread per SOURCE pixel, 2x2 output quad ----------
// out = upsample x2 + reflect-pad + 3x3 + leakyrelu, via 4 phase 2x2 convs.
// Border reflect == clamped 2x2 patch (verified analytically).
template<int CO>
__global__ void k_upconv_q(const float* __restrict__ in, float* __restrict__ out,
                           const float* __restrict__ wq, const float* __restrict__ bias,
                           int B, int Cin, int Hin)
{
  int Hout = Hin * 2;
  int total = B * Hin * Hin;
  int idx = blockIdx.x*blockDim.x + threadIdx.x;
  if (idx >= total) return;
  int sx = idx % Hin;
  int sy = (idx / Hin) % Hin;
  int b  = idx / (Hin * Hin);

  int rofs[3], cofs[3];
  rofs[0] = (sy > 0) ? -Hin : 0;  rofs[1] = 0;  rofs[2] = (sy < Hin-1) ? Hin : 0;
  cofs[0] = (sx > 0) ? -1 : 0;    cofs[1] = 0;  cofs[2] = (sx < Hin-1) ? 1 : 0;

  float acc[CO][4];
  #pragma unroll
  for (int co = 0; co < CO; co++) {
    float bv = bias[co];
    #pragma unroll
    for (int ph = 0; ph < 4; ph++) acc[co][ph] = bv;
  }

  for (int ci = 0; ci < Cin; ci++) {
    const float* ib = in + (((size_t)b*Cin + ci)*Hin + sy)*Hin + sx;
    float p[9];
    #pragma unroll
    for (int dy = 0; dy < 3; dy++)
      #pragma unroll
      for (int dx = 0; dx < 3; dx++)
        p[dy*3+dx] = ib[rofs[dy] + cofs[dx]];

    const float* wqb = wq + (size_t)(ci*CO)*16;
    #pragma unroll
    for (int co = 0; co < CO; co++) {
      const float* wc = wqb + co*16;
      #pragma unroll
      for (int py = 0; py < 2; py++)
        #pragma unroll
        for (int px = 0; px < 2; px++) {
          int ph = py*2 + px;
          #pragma unroll
          for (int ry = 0; ry < 2; ry++)
            #pragma unroll
            for (int rx = 0; rx < 2; rx++)
              acc[co][ph] += wc[(ph*2+ry)*2+rx] * p[(ry+py)*3 + (rx+px)];
        }
    }
  }

  float2* out2 = (float2*)out;
  #pragma unroll
  for (int co = 0; co < CO; co++) {
    #pragma unroll
    for (int py = 0; py < 2; py++) {
      float v0 = acc[co][py*2+0];
      float v1 = acc[co][py*2+1];
      v0 = (v0 >= 0.f) ? v0 : 0.01f*v0;
      v1 = (v1 >= 0.f) ? v1 : 0.01f*v1;
      out2[(((size_t)b*CO + co)*Hout + (2*sy+py))*Hin + sx] = make_float2(v0, v1);
    }
  }
}

// ---------------- final: reflect-pad + 3x3 conv (16 -> 6) + tanh, INTERLEAVED output ----------
// out layout: [b][pix][6]  (channel-fastest, for blend gather locality)
__global__ void k_final(const float* __restrict__ in, float* __restrict__ out,
                        const float* __restrict__ w, const float* __restrict__ bias)
{
  int idx = blockIdx.x*blockDim.x + threadIdx.x;
  int total = 3 * HWP;
  if (idx >= total) return;
  int x = idx & (WWI-1);
  int y = (idx >> 9) & (HH-1);
  int b = idx / HWP;

  int ry[3], rx[3];
  #pragma unroll
  for (int d = 0; d < 3; d++) {
    int t = y - 1 + d;
    t = (t < 0) ? -t : t;
    ry[d] = (t >= HH) ? (2*(HH-1) - t) : t;
    t = x - 1 + d;
    t = (t < 0) ? -t : t;
    rx[d] = (t >= WWI) ? (2*(WWI-1) - t) : t;
  }

  float acc[6];
  #pragma unroll
  for (int co = 0; co < 6; co++) acc[co] = bias[co];

  for (int ci = 0; ci < 16; ci++) {
    const float* ib = in + ((size_t)(b*16) + ci) * HWP;
    float p[9];
    #pragma unroll
    for (int dy = 0; dy < 3; dy++)
      #pragma unroll
      for (int dx = 0; dx < 3; dx++)
        p[dy*3+dx] = ib[ry[dy]*WWI + rx[dx]];
    const float* wc = w + ci*9;
    #pragma unroll
    for (int co = 0; co < 6; co++) {
      const float* wcc = wc + co*16*9;
      #pragma unroll
      for (int k = 0; k < 9; k++) acc[co] += wcc[k] * p[k];
    }
  }

  int pix = y*WWI + x;
  float* o = out + ((size_t)b*HWP + pix)*6;
  #pragma unroll
  for (int co = 0; co < 6; co++)
    o[co] = tanhf(acc[co]);
}

// ---------------- blending (flows interleaved [b][pix][6]) ----------------
__global__ void k_blend(const float* __restrict__ xin, const float* __restrict__ neighbors,
                        const int* __restrict__ aidx, const float* __restrict__ albedos,
                        const float* __restrict__ flows, float* __restrict__ out)
{
  int idx = blockIdx.x*blockDim.x + threadIdx.x;
  if (idx >= HWP) return;
  int xo = idx & (WWI-1);
  int yo = idx >> 9;

  float xv[9];
  #pragma unroll
  for (int i = 0; i < 9; i++) xv[i] = xin[i];

  float f0[6];
  const float* f0p = flows + (size_t)idx*6;
  #pragma unroll
  for (int c = 0; c < 6; c++) f0[c] = f0p[c];

  const float* alb = albedos + (size_t)aidx[0]*3*HWP;
  float albp[3];
  #pragma unroll
  for (int ch = 0; ch < 3; ch++) albp[ch] = alb[(size_t)ch*HWP + idx];

  float num0 = 0.f, num1 = 0.f, num2 = 0.f;
  float wsum = 0.f;

  #pragma unroll
  for (int n = 0; n < 2; n++) {
    float dl = xv[0] - xv[(n+1)*3 + 0];
    float dv = xv[1] - xv[(n+1)*3 + 1];
    float dt = xv[2] - xv[(n+1)*3 + 2];
    bool fl = fabsf(dl) > 0.f;

    float ofx = dl*f0[0] + dv*f0[2] + dt*f0[4];
    float ofy = dl*f0[1] + dv*f0[3] + dt*f0[5];

    float gx = ((-1.f + (2.f/511.f)*(float)xo) + ofx + 1.f)*256.f - 0.5f;
    float gy = ((-1.f + (2.f/511.f)*(float)yo) + ofy + 1.f)*256.f - 0.5f;
    gx = fminf(fmaxf(gx, 0.f), 511.f);
    gy = fminf(fmaxf(gy, 0.f), 511.f);

    float x0f = floorf(gx), y0f = floorf(gy);
    float wx = gx - x0f, wy = gy - y0f;
    int x0i = (int)x0f, y0i = (int)y0f;
    int x1i = min(x0i + 1, WWI-1), y1i = min(y0i + 1, HH-1);

    float cw[4] = {(1.f-wx)*(1.f-wy), wx*(1.f-wy), (1.f-wx)*wy, wx*wy};
    int   cp[4] = {y0i*WWI + x0i, y0i*WWI + x1i, y1i*WWI + x0i, y1i*WWI + x1i};

    const float* nb = neighbors + (size_t)n*3*HWP;
    const float* Fn = flows + (size_t)(n+1)*HWP*6;

    float s0=0.f,s1=0.f,s2=0.f;
    float l0=0.f,l1=0.f,v0=0.f,v1=0.f,t0=0.f,t1=0.f;
    #pragma unroll
    for (int c = 0; c < 4; c++) {
      int p = cp[c];
      float ww = cw[c];
      float n0 = nb[p];
      float n1 = nb[HWP + p];
      float n2 = nb[2*HWP + p];
      if (fl) {
        n0 /= alb[p];
        n1 /= alb[HWP + p];
        n2 /= alb[2*HWP + p];
      }
      s0 += ww*n0; s1 += ww*n1; s2 += ww*n2;
      const float* fp = Fn + (size_t)p*6;
      l0 += ww*fp[0]; l1 += ww*fp[1];
      v0 += ww*fp[2]; v1 += ww*fp[3];
      t0 += ww*fp[4]; t1 += ww*fp[5];
    }

    float wi0 = fl ? s0*albp[0] : s0;
    float wi1 = fl ? s1*albp[1] : s1;
    float wi2 = fl ? s2*albp[2] : s2;

    float obx = dl*l0 + dv*v0 + dt*t0;
    float oby = dl*l1 + dv*v1 + dt*t1;
    float dist = fabsf(ofx - obx) + fabsf(ofy - oby);
    float wgt = expf(-51.2f * dist);

    wsum += wgt;
    num0 += wgt*wi0; num1 += wgt*wi1; num2 += wgt*wi2;
  }

  float inv = 1.f / (wsum + 1e-5f);
  out[idx]         = num0*inv;
  out[HWP + idx]   = num1*inv;
  out[2*HWP + idx] = num2*inv;
}

// ---------------- launch ----------------
extern "C" void kernel_launch(void* const* d_in, const int* in_sizes, int n_in,
                              void* d_out, int out_size, void* d_ws, size_t ws_size,
                              hipStream_t stream) {
  const float* x         = (const float*)d_in[0];
  const float* neighbors = (const float*)d_in[1];
  const int*   aidx      = (const int*)d_in[2];
  const float* wts[10];
  const float* bis[10];
  for (int i = 0; i < 9; i++) { wts[i] = (const float*)d_in[3+2*i]; bis[i] = (const float*)d_in[4+2*i]; }
  wts[9] = (const float*)d_in[21];   // wf
  bis[9] = (const float*)d_in[22];   // bf
  const float* albedos = (const float*)d_in[23];

  float* wk   = (float*)d_ws;
  float* bufS = wk;                   // 792 floats
  float* bufA = wk + 800;             // up to 4,718,592 floats
  float* bufB = bufA + 4718592;       // up to 12,582,912 floats
  float* wq6  = bufB + 12582912;      // 16*32*16 = 8192
  float* wq7  = wq6 + 8192;           // 16*16*16 = 4096
  float* wq8  = wq7 + 4096;           // 4096
  size_t need = (size_t)(800 + 4718592 + 12582912 + 8192 + 4096 + 4096) * 4;
  if (ws_size < need) return;

  // phase-weight tables for L6/L7/L8
  k_mkphase<<<(16*32+255)/256, 256, 0, stream>>>(wts[6], wq6, 16, 32);
  k_mkphase<<<(16*16+255)/256, 256, 0, stream>>>(wts[7], wq7, 16, 16);
  k_mkphase<<<(16*16+255)/256, 256, 0, stream>>>(wts[8], wq8, 16, 16);

  k_layer0<<<1, 256, 0, stream>>>(x, wts[0], bis[0], bufS);

  auto spanOf = [](int Hin, int TR) { int s = TR/2 + 2; return (s > Hin) ? Hin : s; };
  auto ldsB = [&](int COB, int Cin, int Hin, int TR) {
    return (size_t)(COB*Cin*9 + COB + Cin*spanOf(Hin,TR)*Hin) * 4;
  };

  // L1-L5: LDS conv (R7-proven)
  k_conv_lds<1><<<12, 256, ldsB(16,66,2,4), stream>>>(bufS, bufA, wts[1], bis[1],
                                                      3, 66, 64, 16, 2, 4, spanOf(2,4));
  k_conv_lds<1><<<24, 256, ldsB(8,64,4,8), stream>>>(bufA, bufB, wts[2], bis[2],
                                                     3, 64, 64, 8, 4, 8, spanOf(4,8));
  k_conv_lds<2><<<24, 256, ldsB(4,64,8,16), stream>>>(bufB, bufA, wts[3], bis[3],
                                                      3, 64, 32, 4, 8, 16, spanOf(8,16));
  k_conv_lds<2><<<48, 256, ldsB(8,32,16,8), stream>>>(bufA, bufB, wts[4], bis[4],
                                                      3, 32, 32, 8, 16, 8, spanOf(16,8));
  k_conv_lds<4><<<96, 256, ldsB(8,32,32,8), stream>>>(bufB, bufA, wts[5], bis[5],
                                                      3, 32, 32, 8, 32, 8, spanOf(32,8));

  auto blocks = [](int total){ return (total + 255) / 256; };
  // L6-L8: phase-decomposed quad kernels (thread per source pixel)
  k_upconv_q<16><<<blocks(3*64*64),   256, 0, stream>>>(bufA, bufB, wq6, bis[6], 3, 32, 64);
  k_upconv_q<16><<<blocks(3*128*128), 256, 0, stream>>>(bufB, bufA, wq7, bis[7], 3, 16, 128);
  k_upconv_q<16><<<blocks(3*256*256), 256, 0, stream>>>(bufA, bufB, wq8, bis[8], 3, 16, 256);

  k_final<<<blocks(3*HWP), 256, 0, stream>>>(bufB, bufA, wts[9], bis[9]);
  k_blend<<<blocks(HWP), 256, 0, stream>>>(x, neighbors, aidx, albedos, bufA, (float*)d_out);
}